// Round 7
// baseline (367.708 us; speedup 1.0000x reference)
//
#include <hip/hip_runtime.h>
#include <cstdint>

#define NLAYER 3
#define DMODEL 256
#define NHEAD 8
#define HEADD 32
#define FFDIM 1024
#define BATCH 32
#define SEQ 512
#define MTOK (BATCH*SEQ)   // 16384

typedef __attribute__((ext_vector_type(8))) __bf16 bf16x8;
typedef __attribute__((ext_vector_type(4))) __bf16 bf16x4;
typedef __attribute__((ext_vector_type(4))) float f32x4;
typedef __attribute__((ext_vector_type(16))) float f32x16;

typedef __attribute__((address_space(1))) const uint8_t ga_t;
typedef __attribute__((address_space(3))) uint8_t la_t;
__device__ __forceinline__ void gll16(const void* g, void* l) {
    __builtin_amdgcn_global_load_lds((ga_t*)g, (la_t*)l, 16, 0, 0);
}

// ---------------------------------------------------------------------------
// Fused prep (weight transpose->bf16, bias concat) + input projection.
// ---------------------------------------------------------------------------
__global__ __launch_bounds__(256)
void prep_kernel(const float* __restrict__ Wq, const float* __restrict__ Wk,
                 const float* __restrict__ Wv, const float* __restrict__ Wo,
                 const float* __restrict__ W1, const float* __restrict__ W2,
                 const float* __restrict__ bq, const float* __restrict__ bk,
                 const float* __restrict__ bv,
                 __bf16* __restrict__ wqkv, __bf16* __restrict__ wot,
                 __bf16* __restrict__ w1t, __bf16* __restrict__ w2t,
                 float* __restrict__ bqkv,
                 const float* __restrict__ x, const float* __restrict__ Win,
                 const float* __restrict__ bin, __bf16* __restrict__ h16)
{
    const int bid = blockIdx.x;
    const int tid = threadIdx.x;
    if (bid >= 2313) {
        const int m0 = (bid - 2313) * 8;
        const float bv_ = bin[tid];
#pragma unroll
        for (int p = 0; p < 8; ++p) {
            const int m = m0 + p;
            const float* xr = x + (size_t)m * 5;
            float acc = bv_;
#pragma unroll
            for (int k = 0; k < 5; ++k) acc += xr[k] * Win[k * DMODEL + tid];
            h16[(size_t)m * DMODEL + tid] = (__bf16)acc;
        }
        return;
    }
    if (bid >= 3 * 768) {
        int idx = (bid - 3 * 768) * 256 + tid;  // 0..2303
        int l = idx / 768, j = idx % 768;
        float v = (j < 256) ? bq[l * 256 + j]
                : (j < 512) ? bk[l * 256 + j - 256]
                            : bv[l * 256 + j - 512];
        bqkv[idx] = v;
        return;
    }
    const int l = bid / 768;
    const int rr = bid % 768;
    const float* src; __bf16* dst; int K, N, t;
    if (rr < 192) {
        int ty = rr >> 6; t = rr & 63;
        src = (ty == 0 ? Wq : ty == 1 ? Wk : Wv) + (size_t)l * 65536;
        dst = wqkv + (size_t)l * 768 * 256 + (size_t)ty * 65536;
        K = 256; N = 256;
    } else if (rr < 256) {
        t = rr - 192; src = Wo + (size_t)l * 65536; dst = wot + (size_t)l * 65536;
        K = 256; N = 256;
    } else if (rr < 512) {
        t = rr - 256; src = W1 + (size_t)l * 262144; dst = w1t + (size_t)l * 262144;
        K = 256; N = 1024;
    } else {
        t = rr - 512; src = W2 + (size_t)l * 262144; dst = w2t + (size_t)l * 262144;
        K = 1024; N = 256;
    }
    const int tn = N >> 5;
    const int tk = t / tn, tj = t % tn;
    __shared__ float tile[32][33];
    const int c = tid & 31, rbase = tid >> 5;  // rbase 0..7
#pragma unroll
    for (int p = 0; p < 4; ++p) {
        int kr = rbase + p * 8;
        tile[kr][c] = src[(size_t)(tk * 32 + kr) * N + tj * 32 + c];
    }
    __syncthreads();
#pragma unroll
    for (int p = 0; p < 4; ++p) {
        int nr = rbase + p * 8;
        dst[(size_t)(tj * 32 + nr) * K + tk * 32 + c] = (__bf16)tile[c][nr];
    }
}

// ---------------------------------------------------------------------------
// Persistent-B MFMA GEMM for K=256 (QKV, FF1).
// Block 128x128, 256 thr (4 waves 2x2 of 64x64), 2 blocks/CU.
// B panel (128n x 256k = 64 KB) staged ONCE via gll16 with rotated chunks:
//   stored pos = (g + 4*row) & 31  -> b128 frag reads hit all 32 banks.
// A double-buffered 2x8 KB (BK=32), chunk layout [row=m&63][64 elems]
// (col-half = m-bit6), xor chunk swizzle g ^ (row&7) as in the m97 pattern.
// K-loop: per step each wave issues only 2 gll16 for the NEXT A-chunk, then
// 8 ds_read_b128 + 16 MFMA before the barrier -> drain latency hidden.
// ---------------------------------------------------------------------------
template<int RELU>
__global__ __launch_bounds__(256, 2)
void gemm_kernel(const __bf16* __restrict__ A, const __bf16* __restrict__ Bt,
                 const float* __restrict__ bias,
                 __bf16* __restrict__ C, int N)
{
    __shared__ __bf16 Bs[128 * 256];       // 64 KB persistent B panel
    __shared__ __bf16 As[2][64 * 64];      // 2 x 8 KB A k-chunks (BK=32)
    const int tid = threadIdx.x;
    const int m0 = blockIdx.x * 128;
    const int n0 = blockIdx.y * 128;
    const int lane = tid & 63;
    const int wave = tid >> 6;
    const int wm = (wave & 1) * 64;
    const int wn = (wave >> 1) * 64;
    const int fr = lane & 15;
    const int quad = lane >> 4;

    // ---- stage B panel once (16 calls/wave, 2 rows each) ----
    {
        const int rsub = lane >> 5;            // 0/1
#pragma unroll
        for (int c = 0; c < 16; ++c) {
            const int rl = wave * 32 + c * 2 + rsub;
            const int g = ((lane & 31) - 4 * rl) & 31;
            gll16(Bt + (size_t)(n0 + rl) * 256 + g * 8,
                  Bs + (wave * 32 + c * 2) * 256);
        }
    }
    // ---- A chunk staging (2 calls/wave per kstep) ----
    const int arow8 = lane >> 3;               // row within 8-row group
    const int apos = lane & 7;
#define STAGE_A(ks, buf)                                                      \
    {                                                                         \
        _Pragma("unroll")                                                     \
        for (int s_ = 0; s_ < 2; ++s_) {                                      \
            const int c_ = wave * 2 + s_;                                     \
            const int row_ = c_ * 8 + arow8;                                  \
            const int g_ = apos ^ (row_ & 7);                                 \
            gll16(A + (size_t)(m0 + row_ + 64 * (g_ >> 2)) * 256              \
                    + (ks) * 32 + (g_ & 3) * 8,                               \
                  &As[buf][c_ * 8 * 64]);                                     \
        }                                                                     \
    }
    STAGE_A(0, 0);
    __syncthreads();

    f32x4 acc[4][4];
#pragma unroll
    for (int i = 0; i < 4; ++i)
#pragma unroll
        for (int j = 0; j < 4; ++j)
#pragma unroll
            for (int r = 0; r < 4; ++r) acc[i][j][r] = 0.f;

    const int aposr = ((wave & 1) * 4 + quad) ^ (fr & 7);

#pragma unroll
    for (int ks = 0; ks < 8; ++ks) {
        if (ks < 7) STAGE_A(ks + 1, (ks + 1) & 1);
        const __bf16* Ab = As[ks & 1];
        bf16x8 af[4], bfr[4];
#pragma unroll
        for (int i = 0; i < 4; ++i) {
            const int row = i * 16 + fr;
            af[i] = *(const bf16x8*)(Ab + row * 64 + aposr * 8);
        }
#pragma unroll
        for (int j = 0; j < 4; ++j) {
            const int row = wn + j * 16 + fr;
            const int pos = (ks * 4 + quad + 4 * fr) & 31;
            bfr[j] = *(const bf16x8*)(Bs + row * 256 + pos * 8);
        }
#pragma unroll
        for (int i = 0; i < 4; ++i)
#pragma unroll
            for (int j = 0; j < 4; ++j)
                acc[i][j] = __builtin_amdgcn_mfma_f32_16x16x32_bf16(
                    af[i], bfr[j], acc[i][j], 0, 0, 0);
        __syncthreads();
    }
#undef STAGE_A

    // ---- epilogue ----
#pragma unroll
    for (int i = 0; i < 4; ++i) {
#pragma unroll
        for (int j = 0; j < 4; ++j) {
            const int gc = n0 + wn + j * 16 + fr;
            const float bv = bias[gc];
#pragma unroll
            for (int r = 0; r < 4; ++r) {
                const int gr = m0 + wm + i * 16 + quad * 4 + r;
                float v = acc[i][j][r] + bv;
                if (RELU) v = fmaxf(v, 0.f);
                C[(size_t)gr * N + gc] = (__bf16)v;
            }
        }
    }
}

// ---------------------------------------------------------------------------
// Fused GEMM + residual + LayerNorm, N=256. 32x256 tile, grid M/32 = 512.
// (unchanged from round 6)
// ---------------------------------------------------------------------------
template<int LAST>
__global__ __launch_bounds__(256, 4)
void gemm_ln_kernel(const __bf16* __restrict__ A, const __bf16* __restrict__ Bt,
                    const float* __restrict__ bias, const __bf16* __restrict__ res,
                    const float* __restrict__ g, const float* __restrict__ be,
                    __bf16* __restrict__ out16, float* __restrict__ out32, int K)
{
    __shared__ __bf16 As[32 * 64];    //  4 KB
    __shared__ __bf16 Bs[256 * 64];   // 32 KB
    __shared__ float red[32 * 8];     //  1 KB
    const int tid = threadIdx.x;
    const int m0 = blockIdx.x * 32;
    const int lane = tid & 63;
    const int wave = tid >> 6;            // 0..3
    const int wn = wave * 64;
    const int fr = lane & 15;
    const int quad = lane >> 4;
    const int lr = lane >> 3;
    const int qg = (lane & 7) ^ lr;
    const int frs = fr & 7;

    const __bf16* Ab = A  + (size_t)(m0 + wave * 8 + lr) * K + qg * 8;
    const __bf16* Bb = Bt + (size_t)(wave * 64 + lr) * K + qg * 8;

    f32x4 acc[2][4];
#pragma unroll
    for (int i = 0; i < 2; ++i)
#pragma unroll
        for (int j = 0; j < 4; ++j)
#pragma unroll
            for (int r = 0; r < 4; ++r) acc[i][j][r] = 0.f;

    for (int k0 = 0; k0 < K; k0 += 64) {
        gll16(Ab + k0, As + wave * 512);
#pragma unroll
        for (int p = 0; p < 8; ++p)
            gll16(Bb + (size_t)p * 8 * K + k0, Bs + (wave * 8 + p) * 512);
        __syncthreads();
#pragma unroll
        for (int kk = 0; kk < 2; ++kk) {
            bf16x8 af[2], bfr[4];
#pragma unroll
            for (int i = 0; i < 2; ++i) {
                int row = i * 16 + fr;
                af[i] = *(const bf16x8*)(As + row * 64 + (((kk * 4 + quad) ^ frs) * 8));
            }
#pragma unroll
            for (int j = 0; j < 4; ++j) {
                int row = wn + j * 16 + fr;
                bfr[j] = *(const bf16x8*)(Bs + row * 64 + (((kk * 4 + quad) ^ frs) * 8));
            }
#pragma unroll
            for (int i = 0; i < 2; ++i)
#pragma unroll
                for (int j = 0; j < 4; ++j)
                    acc[i][j] = __builtin_amdgcn_mfma_f32_16x16x32_bf16(
                        af[i], bfr[j], acc[i][j], 0, 0, 0);
        }
        __syncthreads();
    }

    float bv[4];
#pragma unroll
    for (int j = 0; j < 4; ++j) bv[j] = bias[wn + j * 16 + fr];

#pragma unroll
    for (int i = 0; i < 2; ++i) {
#pragma unroll
        for (int r = 0; r < 4; ++r) {
            const int row = i * 16 + quad * 4 + r;     // 0..31
            float ps = 0.f, pq = 0.f;
#pragma unroll
            for (int j = 0; j < 4; ++j) {
                const int gc = wn + j * 16 + fr;
                float v = acc[i][j][r] + bv[j]
                        + (float)res[(size_t)(m0 + row) * DMODEL + gc];
                acc[i][j][r] = v;
                ps += v;
                pq += v * v;
            }
#pragma unroll
            for (int off = 1; off < 16; off <<= 1) {
                ps += __shfl_xor(ps, off, 64);
                pq += __shfl_xor(pq, off, 64);
            }
            if (fr == 0) {
                red[row * 8 + wave * 2]     = ps;
                red[row * 8 + wave * 2 + 1] = pq;
            }
        }
    }
    __syncthreads();

#pragma unroll
    for (int i = 0; i < 2; ++i) {
#pragma unroll
        for (int r = 0; r < 4; ++r) {
            const int row = i * 16 + quad * 4 + r;
            f32x4 a = *(const f32x4*)(red + row * 8);
            f32x4 b2 = *(const f32x4*)(red + row * 8 + 4);
            const float s  = a[0] + a[2] + b2[0] + b2[2];
            const float sq = a[1] + a[3] + b2[1] + b2[3];
            const float mu = s * (1.f / DMODEL);
            const float var = sq * (1.f / DMODEL) - mu * mu;
            const float rs = rsqrtf(var + 1e-5f);
#pragma unroll
            for (int j = 0; j < 4; ++j) {
                const int gc = wn + j * 16 + fr;
                float y = (acc[i][j][r] - mu) * rs * g[gc] + be[gc];
                if (LAST) out32[(size_t)(m0 + row) * DMODEL + gc] = y;
                else      out16[(size_t)(m0 + row) * DMODEL + gc] = (__bf16)y;
            }
        }
    }
}

// ---------------------------------------------------------------------------
// MFMA flash attention, 32x32 tiles. One block per (b,h). (unchanged)
// ---------------------------------------------------------------------------
__global__ __launch_bounds__(1024)
void attn_kernel(const __bf16* __restrict__ qkv, const int* __restrict__ mask,
                 __bf16* __restrict__ ao)
{
    __shared__ __bf16 Ks[512 * 40];      // 40960 B
    __shared__ __bf16 Vt[32 * 520];      // 33280 B
    __shared__ __bf16 Pq[16 * 32 * 40];  // 40960 B
    __shared__ float maskadd[512];       //  2048 B

    const int b = blockIdx.x >> 3;
    const int h = blockIdx.x & 7;
    const int t = threadIdx.x;
    const int lane = t & 63;
    const int wave = t >> 6;             // 0..15
    const int cl = lane & 31;
    const int kh = lane >> 5;
    const float scale = 0.17677669529663687f;  // 1/sqrt(32)

    const size_t base = (size_t)b * SEQ * 768;

#pragma unroll
    for (int p = 0; p < 2; ++p) {
        int idx = p * 1024 + t;          // 0..2047
        int key = idx >> 2, ch = idx & 3;
        bf16x8 kv = *(const bf16x8*)(qkv + base + (size_t)key * 768 + 256 + h * 32 + ch * 8);
        *(bf16x8*)(Ks + key * 40 + ch * 8) = kv;
        bf16x8 vv = *(const bf16x8*)(qkv + base + (size_t)key * 768 + 512 + h * 32 + ch * 8);
#pragma unroll
        for (int j = 0; j < 8; ++j) Vt[(ch * 8 + j) * 520 + key] = vv[j];
    }
    if (t < 512) maskadd[t] = mask[b * SEQ + t] ? -1e30f : 0.f;
    __syncthreads();

    const int q0 = wave * 32;
    const __bf16* qrow = qkv + base + (size_t)(q0 + cl) * 768 + h * 32;
    bf16x8 qf0 = *(const bf16x8*)(qrow + kh * 8);
    bf16x8 qf1 = *(const bf16x8*)(qrow + 16 + kh * 8);

    f32x16 oacc;
#pragma unroll
    for (int i = 0; i < 16; ++i) oacc[i] = 0.f;
    float lsum = 0.f;
    __bf16* Pw = Pq + wave * 32 * 40;

    for (int kt = 0; kt < SEQ; kt += 32) {
        bf16x8 kf0 = *(const bf16x8*)(Ks + (kt + cl) * 40 + kh * 8);
        bf16x8 kf1 = *(const bf16x8*)(Ks + (kt + cl) * 40 + 16 + kh * 8);
        f32x16 s;
#pragma unroll
        for (int i = 0; i < 16; ++i) s[i] = 0.f;
        s = __builtin_amdgcn_mfma_f32_32x32x16_bf16(kf0, qf0, s, 0, 0, 0);
        s = __builtin_amdgcn_mfma_f32_32x32x16_bf16(kf1, qf1, s, 0, 0, 0);
        float pv[16];
#pragma unroll
        for (int g = 0; g < 4; ++g) {
            f32x4 mv = *(const f32x4*)(maskadd + kt + 8 * g + 4 * kh);
#pragma unroll
            for (int r = 0; r < 4; ++r) {
                float e = __expf(s[g * 4 + r] * scale + mv[r]);
                pv[g * 4 + r] = e;
                lsum += e;
            }
        }
#pragma unroll
        for (int g = 0; g < 4; ++g) {
            bf16x4 pb;
#pragma unroll
            for (int r = 0; r < 4; ++r) pb[r] = (__bf16)pv[g * 4 + r];
            *(bf16x4*)(Pw + cl * 40 + 8 * g + 4 * kh) = pb;
        }
        bf16x8 pf0 = *(const bf16x8*)(Pw + cl * 40 + kh * 8);
        bf16x8 pf1 = *(const bf16x8*)(Pw + cl * 40 + 16 + kh * 8);
        bf16x8 vf0 = *(const bf16x8*)(Vt + cl * 520 + kt + kh * 8);
        bf16x8 vf1 = *(const bf16x8*)(Vt + cl * 520 + kt + 16 + kh * 8);
        oacc = __builtin_amdgcn_mfma_f32_32x32x16_bf16(vf0, pf0, oacc, 0, 0, 0);
        oacc = __builtin_amdgcn_mfma_f32_32x32x16_bf16(vf1, pf1, oacc, 0, 0, 0);
    }

    lsum += __shfl_xor(lsum, 32);
    const float inv = (lsum > 0.f) ? 1.f / lsum : 0.f;
    __bf16* orow = ao + (size_t)(b * SEQ + q0 + cl) * DMODEL + h * 32;
#pragma unroll
    for (int g = 0; g < 4; ++g) {
        bf16x4 w;
#pragma unroll
        for (int r = 0; r < 4; ++r) w[r] = (__bf16)(oacc[g * 4 + r] * inv);
        *(bf16x4*)(orow + 8 * g + 4 * kh) = w;
    }
}

// ---------------------------------------------------------------------------
extern "C" void kernel_launch(void* const* d_in, const int* in_sizes, int n_in,
                              void* d_out, int out_size, void* d_ws, size_t ws_size,
                              hipStream_t stream)
{
    const float* x   = (const float*)d_in[0];
    const int*   mask= (const int*)d_in[1];
    const float* Win = (const float*)d_in[2];
    const float* bin = (const float*)d_in[3];
    const float* Wq  = (const float*)d_in[4];
    const float* bq  = (const float*)d_in[5];
    const float* Wk  = (const float*)d_in[6];
    const float* bk  = (const float*)d_in[7];
    const float* Wv  = (const float*)d_in[8];
    const float* bv  = (const float*)d_in[9];
    const float* Wo  = (const float*)d_in[10];
    const float* bo  = (const float*)d_in[11];
    const float* g1  = (const float*)d_in[12];
    const float* b1  = (const float*)d_in[13];
    const float* W1  = (const float*)d_in[14];
    const float* c1  = (const float*)d_in[15];
    const float* W2  = (const float*)d_in[16];
    const float* c2  = (const float*)d_in[17];
    const float* g2  = (const float*)d_in[18];
    const float* b2  = (const float*)d_in[19];

    char* ws = (char*)d_ws;
    size_t off = 0;
    auto alloc = [&](size_t bytes) -> void* {
        void* p = ws + off;
        off += (bytes + 255) & ~(size_t)255;
        return p;
    };
    __bf16* hA   = (__bf16*)alloc((size_t)MTOK * 256 * 2);  // 8 MB (residual)
    __bf16* hB   = (__bf16*)alloc((size_t)MTOK * 256 * 2);  // 8 MB (LN1 out)
    __bf16* u    = (__bf16*)alloc((size_t)MTOK * 1024 * 2); // 32 MB (qkv / ff union)
    __bf16* qkv  = u;
    __bf16* ffT  = u;
    __bf16* ao   = (__bf16*)alloc((size_t)MTOK * 256 * 2);  // 8 MB
    __bf16* wqkv = (__bf16*)alloc((size_t)3 * 768 * 256 * 2);
    __bf16* wot  = (__bf16*)alloc((size_t)3 * 256 * 256 * 2);
    __bf16* w1t  = (__bf16*)alloc((size_t)3 * 1024 * 256 * 2);
    __bf16* w2t  = (__bf16*)alloc((size_t)3 * 256 * 1024 * 2);
    float*  bqkv = (float*)alloc((size_t)3 * 768 * 4);

    prep_kernel<<<dim3(2313 + MTOK / 8), dim3(256), 0, stream>>>(
        Wq, Wk, Wv, Wo, W1, W2, bq, bk, bv, wqkv, wot, w1t, w2t, bqkv,
        x, Win, bin, hA);

    for (int l = 0; l < NLAYER; ++l) {
        // QKV: [16384,256]bf16 @ [256,768] -> bf16 qkv  (persistent-B)
        gemm_kernel<0><<<dim3(128, 6), dim3(256), 0, stream>>>(
            hA, wqkv + (size_t)l * 768 * 256, bqkv + l * 768, qkv, 768);
        // flash attention (one block per (b,h))
        attn_kernel<<<dim3(256), dim3(1024), 0, stream>>>(qkv, mask, ao);
        // Wo + residual + LN1 fused: hB = LN(hA + ao@Wo + bo)
        gemm_ln_kernel<0><<<dim3(MTOK / 32), dim3(256), 0, stream>>>(
            ao, wot + (size_t)l * 65536, bo + l * 256, hA,
            g1 + l * 256, b1 + l * 256, hB, nullptr, 256);
        // FF1: relu(hB@W1 + c1) -> bf16 ffT  (persistent-B)
        gemm_kernel<1><<<dim3(128, 8), dim3(256), 0, stream>>>(
            hB, w1t + (size_t)l * 262144, c1 + l * 1024, ffT, 1024);
        // FF2 + residual + LN2 fused: hA = LN(hB + ffT@W2 + c2)  (last -> d_out)
        if (l == 2) {
            gemm_ln_kernel<1><<<dim3(MTOK / 32), dim3(256), 0, stream>>>(
                ffT, w2t + (size_t)l * 262144, c2 + l * 256, hB,
                g2 + l * 256, b2 + l * 256, nullptr, (float*)d_out, 1024);
        } else {
            gemm_ln_kernel<0><<<dim3(MTOK / 32), dim3(256), 0, stream>>>(
                ffT, w2t + (size_t)l * 262144, c2 + l * 256, hB,
                g2 + l * 256, b2 + l * 256, hA, nullptr, 1024);
        }
    }
}

// Round 8
// 359.663 us; speedup vs baseline: 1.0224x; 1.0224x over previous
//
#include <hip/hip_runtime.h>
#include <cstdint>

#define NLAYER 3
#define DMODEL 256
#define NHEAD 8
#define HEADD 32
#define FFDIM 1024
#define BATCH 32
#define SEQ 512
#define MTOK (BATCH*SEQ)   // 16384

typedef __attribute__((ext_vector_type(8))) __bf16 bf16x8;
typedef __attribute__((ext_vector_type(4))) __bf16 bf16x4;
typedef __attribute__((ext_vector_type(4))) float f32x4;
typedef __attribute__((ext_vector_type(16))) float f32x16;

typedef __attribute__((address_space(1))) const uint8_t ga_t;
typedef __attribute__((address_space(3))) uint8_t la_t;
__device__ __forceinline__ void gll16(const void* g, void* l) {
    __builtin_amdgcn_global_load_lds((ga_t*)g, (la_t*)l, 16, 0, 0);
}

// ---------------------------------------------------------------------------
// Prep: wqkv/wot transposed bf16 [N][K]; W1/W2 packed in MFMA B-fragment
// order: frag (ntile, kstep) = 64 lanes x 16B, lane = quad*16+fr, elements
// = Wt[ntile*16+fr][kstep*32 + quad*8 .. +8]. Kernel-side B-frag load is then
// one coalesced 16B/lane global load (L2-resident), no LDS staging.
// Plus bias concat and input projection.
// ---------------------------------------------------------------------------
__global__ __launch_bounds__(256)
void prep_kernel(const float* __restrict__ Wq, const float* __restrict__ Wk,
                 const float* __restrict__ Wv, const float* __restrict__ Wo,
                 const float* __restrict__ W1, const float* __restrict__ W2,
                 const float* __restrict__ bq, const float* __restrict__ bk,
                 const float* __restrict__ bv,
                 __bf16* __restrict__ wqkv, __bf16* __restrict__ wot,
                 __bf16* __restrict__ w1f, __bf16* __restrict__ w2f,
                 float* __restrict__ bqkv,
                 const float* __restrict__ x, const float* __restrict__ Win,
                 const float* __restrict__ bin, __bf16* __restrict__ h16)
{
    const int bid = blockIdx.x;
    const int tid = threadIdx.x;
    if (bid >= 2313) {
        const int m0 = (bid - 2313) * 8;
        const float bv_ = bin[tid];
#pragma unroll
        for (int p = 0; p < 8; ++p) {
            const int m = m0 + p;
            const float* xr = x + (size_t)m * 5;
            float acc = bv_;
#pragma unroll
            for (int k = 0; k < 5; ++k) acc += xr[k] * Win[k * DMODEL + tid];
            h16[(size_t)m * DMODEL + tid] = (__bf16)acc;
        }
        return;
    }
    if (bid >= 3 * 768) {
        int idx = (bid - 3 * 768) * 256 + tid;  // 0..2303
        int l = idx / 768, j = idx % 768;
        float v = (j < 256) ? bq[l * 256 + j]
                : (j < 512) ? bk[l * 256 + j - 256]
                            : bv[l * 256 + j - 512];
        bqkv[idx] = v;
        return;
    }
    const int l = bid / 768;
    const int rr = bid % 768;
    __shared__ float tile[32][33];
    const int c = tid & 31, rbase = tid >> 5;

    if (rr < 256) {
        // ---- transposed bf16 [N=256][K=256] for wqkv / wot ----
        const float* src; __bf16* dst; int t;
        if (rr < 192) {
            int ty = rr >> 6; t = rr & 63;
            src = (ty == 0 ? Wq : ty == 1 ? Wk : Wv) + (size_t)l * 65536;
            dst = wqkv + (size_t)l * 768 * 256 + (size_t)ty * 65536;
        } else {
            t = rr - 192; src = Wo + (size_t)l * 65536; dst = wot + (size_t)l * 65536;
        }
        const int tk = t >> 3, tj = t & 7;
#pragma unroll
        for (int p = 0; p < 4; ++p) {
            int kr = rbase + p * 8;
            tile[kr][c] = src[(size_t)(tk * 32 + kr) * 256 + tj * 32 + c];
        }
        __syncthreads();
#pragma unroll
        for (int p = 0; p < 4; ++p) {
            int nr = rbase + p * 8;
            dst[(size_t)(tj * 32 + nr) * 256 + tk * 32 + c] = (__bf16)tile[c][nr];
        }
        return;
    }
    // ---- fragment-packed W1 / W2 ----
    const float* src; __bf16* dst; int N, KT, t;
    if (rr < 512) { t = rr - 256; src = W1 + (size_t)l * 262144;
                    dst = w1f + (size_t)l * 262144; N = 1024; KT = 8; }
    else          { t = rr - 512; src = W2 + (size_t)l * 262144;
                    dst = w2f + (size_t)l * 262144; N = 256;  KT = 32; }
    const int tn = N >> 5;
    const int tk = t / tn, tj = t % tn;
#pragma unroll
    for (int p = 0; p < 4; ++p) {
        int kr = rbase + p * 8;
        tile[kr][c] = src[(size_t)(tk * 32 + kr) * N + tj * 32 + c];
    }
    __syncthreads();
    if (tid < 128) {
        const int l_n = tid >> 2, k8 = tid & 3;
        const int n = tj * 32 + l_n;
        bf16x8 v;
#pragma unroll
        for (int j = 0; j < 8; ++j) v[j] = (__bf16)tile[k8 * 8 + j][l_n];
        *(bf16x8*)(dst + ((size_t)((n >> 4) * KT + tk) * 64 + k8 * 16 + (n & 15)) * 8) = v;
    }
}

// ---------------------------------------------------------------------------
// Persistent-B MFMA GEMM for K=256 (QKV). Unchanged from round 7.
// ---------------------------------------------------------------------------
template<int RELU>
__global__ __launch_bounds__(256, 2)
void gemm_kernel(const __bf16* __restrict__ A, const __bf16* __restrict__ Bt,
                 const float* __restrict__ bias,
                 __bf16* __restrict__ C, int N)
{
    __shared__ __bf16 Bs[128 * 256];
    __shared__ __bf16 As[2][64 * 64];
    const int tid = threadIdx.x;
    const int m0 = blockIdx.x * 128;
    const int n0 = blockIdx.y * 128;
    const int lane = tid & 63;
    const int wave = tid >> 6;
    const int wm = (wave & 1) * 64;
    const int wn = (wave >> 1) * 64;
    const int fr = lane & 15;
    const int quad = lane >> 4;

    {
        const int rsub = lane >> 5;
#pragma unroll
        for (int c = 0; c < 16; ++c) {
            const int rl = wave * 32 + c * 2 + rsub;
            const int g = ((lane & 31) - 4 * rl) & 31;
            gll16(Bt + (size_t)(n0 + rl) * 256 + g * 8,
                  Bs + (wave * 32 + c * 2) * 256);
        }
    }
    const int arow8 = lane >> 3;
    const int apos = lane & 7;
#define STAGE_A(ks, buf)                                                      \
    {                                                                         \
        _Pragma("unroll")                                                     \
        for (int s_ = 0; s_ < 2; ++s_) {                                      \
            const int c_ = wave * 2 + s_;                                     \
            const int row_ = c_ * 8 + arow8;                                  \
            const int g_ = apos ^ (row_ & 7);                                 \
            gll16(A + (size_t)(m0 + row_ + 64 * (g_ >> 2)) * 256              \
                    + (ks) * 32 + (g_ & 3) * 8,                               \
                  &As[buf][c_ * 8 * 64]);                                     \
        }                                                                     \
    }
    STAGE_A(0, 0);
    __syncthreads();

    f32x4 acc[4][4];
#pragma unroll
    for (int i = 0; i < 4; ++i)
#pragma unroll
        for (int j = 0; j < 4; ++j)
#pragma unroll
            for (int r = 0; r < 4; ++r) acc[i][j][r] = 0.f;

    const int aposr = ((wave & 1) * 4 + quad) ^ (fr & 7);

#pragma unroll
    for (int ks = 0; ks < 8; ++ks) {
        if (ks < 7) STAGE_A(ks + 1, (ks + 1) & 1);
        const __bf16* Ab = As[ks & 1];
        bf16x8 af[4], bfr[4];
#pragma unroll
        for (int i = 0; i < 4; ++i) {
            const int row = i * 16 + fr;
            af[i] = *(const bf16x8*)(Ab + row * 64 + aposr * 8);
        }
#pragma unroll
        for (int j = 0; j < 4; ++j) {
            const int row = wn + j * 16 + fr;
            const int pos = (ks * 4 + quad + 4 * fr) & 31;
            bfr[j] = *(const bf16x8*)(Bs + row * 256 + pos * 8);
        }
#pragma unroll
        for (int i = 0; i < 4; ++i)
#pragma unroll
            for (int j = 0; j < 4; ++j)
                acc[i][j] = __builtin_amdgcn_mfma_f32_16x16x32_bf16(
                    af[i], bfr[j], acc[i][j], 0, 0, 0);
        __syncthreads();
    }
#undef STAGE_A

#pragma unroll
    for (int i = 0; i < 4; ++i) {
#pragma unroll
        for (int j = 0; j < 4; ++j) {
            const int gc = n0 + wn + j * 16 + fr;
            const float bv = bias[gc];
#pragma unroll
            for (int r = 0; r < 4; ++r) {
                const int gr = m0 + wm + i * 16 + quad * 4 + r;
                float v = acc[i][j][r] + bv;
                if (RELU) v = fmaxf(v, 0.f);
                C[(size_t)gr * N + gc] = (__bf16)v;
            }
        }
    }
}

// ---------------------------------------------------------------------------
// Fused GEMM + residual + LayerNorm, N=256 (Wo path). Unchanged from round 6.
// ---------------------------------------------------------------------------
template<int LAST>
__global__ __launch_bounds__(256, 4)
void gemm_ln_kernel(const __bf16* __restrict__ A, const __bf16* __restrict__ Bt,
                    const float* __restrict__ bias, const __bf16* __restrict__ res,
                    const float* __restrict__ g, const float* __restrict__ be,
                    __bf16* __restrict__ out16, float* __restrict__ out32, int K)
{
    __shared__ __bf16 As[32 * 64];
    __shared__ __bf16 Bs[256 * 64];
    __shared__ float red[32 * 8];
    const int tid = threadIdx.x;
    const int m0 = blockIdx.x * 32;
    const int lane = tid & 63;
    const int wave = tid >> 6;
    const int wn = wave * 64;
    const int fr = lane & 15;
    const int quad = lane >> 4;
    const int lr = lane >> 3;
    const int qg = (lane & 7) ^ lr;
    const int frs = fr & 7;

    const __bf16* Ab = A  + (size_t)(m0 + wave * 8 + lr) * K + qg * 8;
    const __bf16* Bb = Bt + (size_t)(wave * 64 + lr) * K + qg * 8;

    f32x4 acc[2][4];
#pragma unroll
    for (int i = 0; i < 2; ++i)
#pragma unroll
        for (int j = 0; j < 4; ++j)
#pragma unroll
            for (int r = 0; r < 4; ++r) acc[i][j][r] = 0.f;

    for (int k0 = 0; k0 < K; k0 += 64) {
        gll16(Ab + k0, As + wave * 512);
#pragma unroll
        for (int p = 0; p < 8; ++p)
            gll16(Bb + (size_t)p * 8 * K + k0, Bs + (wave * 8 + p) * 512);
        __syncthreads();
#pragma unroll
        for (int kk = 0; kk < 2; ++kk) {
            bf16x8 af[2], bfr[4];
#pragma unroll
            for (int i = 0; i < 2; ++i) {
                int row = i * 16 + fr;
                af[i] = *(const bf16x8*)(As + row * 64 + (((kk * 4 + quad) ^ frs) * 8));
            }
#pragma unroll
            for (int j = 0; j < 4; ++j) {
                int row = wn + j * 16 + fr;
                bfr[j] = *(const bf16x8*)(Bs + row * 64 + (((kk * 4 + quad) ^ frs) * 8));
            }
#pragma unroll
            for (int i = 0; i < 2; ++i)
#pragma unroll
                for (int j = 0; j < 4; ++j)
                    acc[i][j] = __builtin_amdgcn_mfma_f32_16x16x32_bf16(
                        af[i], bfr[j], acc[i][j], 0, 0, 0);
        }
        __syncthreads();
    }

    float bv[4];
#pragma unroll
    for (int j = 0; j < 4; ++j) bv[j] = bias[wn + j * 16 + fr];

#pragma unroll
    for (int i = 0; i < 2; ++i) {
#pragma unroll
        for (int r = 0; r < 4; ++r) {
            const int row = i * 16 + quad * 4 + r;
            float ps = 0.f, pq = 0.f;
#pragma unroll
            for (int j = 0; j < 4; ++j) {
                const int gc = wn + j * 16 + fr;
                float v = acc[i][j][r] + bv[j]
                        + (float)res[(size_t)(m0 + row) * DMODEL + gc];
                acc[i][j][r] = v;
                ps += v;
                pq += v * v;
            }
#pragma unroll
            for (int off = 1; off < 16; off <<= 1) {
                ps += __shfl_xor(ps, off, 64);
                pq += __shfl_xor(pq, off, 64);
            }
            if (fr == 0) {
                red[row * 8 + wave * 2]     = ps;
                red[row * 8 + wave * 2 + 1] = pq;
            }
        }
    }
    __syncthreads();

#pragma unroll
    for (int i = 0; i < 2; ++i) {
#pragma unroll
        for (int r = 0; r < 4; ++r) {
            const int row = i * 16 + quad * 4 + r;
            f32x4 a = *(const f32x4*)(red + row * 8);
            f32x4 b2 = *(const f32x4*)(red + row * 8 + 4);
            const float s  = a[0] + a[2] + b2[0] + b2[2];
            const float sq = a[1] + a[3] + b2[1] + b2[3];
            const float mu = s * (1.f / DMODEL);
            const float var = sq * (1.f / DMODEL) - mu * mu;
            const float rs = rsqrtf(var + 1e-5f);
#pragma unroll
            for (int j = 0; j < 4; ++j) {
                const int gc = wn + j * 16 + fr;
                float y = (acc[i][j][r] - mu) * rs * g[gc] + be[gc];
                if (LAST) out32[(size_t)(m0 + row) * DMODEL + gc] = y;
                else      out16[(size_t)(m0 + row) * DMODEL + gc] = (__bf16)y;
            }
        }
    }
}

// ---------------------------------------------------------------------------
// Fully fused FF block: out = LN(res + relu(A@W1+c1)@W2 + c2).
// Grid 512 (32 rows/block), 256 thr (4 waves). A staged once (16 KB, xor
// swizzle). Loop over 8 chunks of 128 FF dims: FF1 (W1 frags direct from
// global/L2) -> relu+c1 -> P in LDS (stride 136: 16B aligned, 2-way banks)
// -> FF2 partial (W2 frags direct from global/L2). The 1024-wide
// intermediate never touches HBM. Epilogue = gemm_ln's.
// ---------------------------------------------------------------------------
template<int LAST>
__global__ __launch_bounds__(256, 3)
void ff_kernel(const __bf16* __restrict__ A, const __bf16* __restrict__ w1f,
               const float* __restrict__ c1, const __bf16* __restrict__ w2f,
               const float* __restrict__ c2, const __bf16* __restrict__ res,
               const float* __restrict__ g, const float* __restrict__ be,
               __bf16* __restrict__ out16, float* __restrict__ out32)
{
    __shared__ __attribute__((aligned(16))) __bf16 As[4][32 * 64];  // 16 KB
    __shared__ __attribute__((aligned(16))) __bf16 P[32 * 136];     // 8.5 KB
    __shared__ float c1s[1024];                                      // 4 KB
    __shared__ float red[32 * 8];                                    // 1 KB
    const int tid = threadIdx.x;
    const int lane = tid & 63;
    const int wave = tid >> 6;
    const int fr = lane & 15;
    const int quad = lane >> 4;
    const int m0 = blockIdx.x * 32;
    const int frs = fr & 7;

    // ---- stage A tile (wave w stages k-chunk w) ----
    {
        const int lr = lane >> 3, pos = lane & 7;
#pragma unroll
        for (int c4 = 0; c4 < 4; ++c4) {
            const int row = c4 * 8 + lr;
            const int gsw = pos ^ (row & 7);
            gll16(A + (size_t)(m0 + row) * 256 + wave * 64 + gsw * 8,
                  &As[wave][c4 * 8 * 64]);
        }
    }
    // c1 to LDS
    *(f32x4*)(c1s + tid * 4) = *(const f32x4*)(c1 + tid * 4);

    f32x4 acc2[2][4];
#pragma unroll
    for (int i = 0; i < 2; ++i)
#pragma unroll
        for (int j = 0; j < 4; ++j)
#pragma unroll
            for (int r = 0; r < 4; ++r) acc2[i][j][r] = 0.f;
    __syncthreads();

    for (int ch = 0; ch < 8; ++ch) {
        // ---- FF1: S[32 x 128-chunk]; wave owns cols [wave*32, wave*32+32) ----
        f32x4 acc1[2][2];
#pragma unroll
        for (int i = 0; i < 2; ++i)
#pragma unroll
            for (int j = 0; j < 2; ++j)
#pragma unroll
                for (int r = 0; r < 4; ++r) acc1[i][j][r] = 0.f;
#pragma unroll
        for (int ks = 0; ks < 8; ++ks) {
            bf16x8 af[2], bfr[2];
#pragma unroll
            for (int i = 0; i < 2; ++i)
                af[i] = *(const bf16x8*)(&As[ks >> 1][(i * 16 + fr) * 64
                         + ((((ks & 1) * 4 + quad) ^ frs) * 8)]);
#pragma unroll
            for (int j = 0; j < 2; ++j) {
                const int ntf = ch * 8 + wave * 2 + j;
                bfr[j] = *(const bf16x8*)(w1f + ((size_t)(ntf * 8 + ks) * 64 + lane) * 8);
            }
#pragma unroll
            for (int i = 0; i < 2; ++i)
#pragma unroll
                for (int j = 0; j < 2; ++j)
                    acc1[i][j] = __builtin_amdgcn_mfma_f32_16x16x32_bf16(
                        af[i], bfr[j], acc1[i][j], 0, 0, 0);
        }
        // relu + bias, write P^ (C-layout scatter, bf16)
#pragma unroll
        for (int j = 0; j < 2; ++j) {
            const float cb = c1s[ch * 128 + wave * 32 + j * 16 + fr];
#pragma unroll
            for (int i = 0; i < 2; ++i)
#pragma unroll
                for (int r = 0; r < 4; ++r) {
                    const int rowm = i * 16 + quad * 4 + r;
                    float v = fmaxf(acc1[i][j][r] + cb, 0.f);
                    P[rowm * 136 + wave * 32 + j * 16 + fr] = (__bf16)v;
                }
        }
        __syncthreads();
        // ---- FF2 partial: acc2 += P @ W2chunk ----
#pragma unroll
        for (int ks = 0; ks < 4; ++ks) {
            bf16x8 pf[2], wf[4];
#pragma unroll
            for (int i = 0; i < 2; ++i)
                pf[i] = *(const bf16x8*)(P + (i * 16 + fr) * 136 + ks * 32 + quad * 8);
#pragma unroll
            for (int j = 0; j < 4; ++j) {
                const int ntg = wave * 4 + j;
                const int kt = ch * 4 + ks;
                wf[j] = *(const bf16x8*)(w2f + ((size_t)(ntg * 32 + kt) * 64 + lane) * 8);
            }
#pragma unroll
            for (int i = 0; i < 2; ++i)
#pragma unroll
                for (int j = 0; j < 4; ++j)
                    acc2[i][j] = __builtin_amdgcn_mfma_f32_16x16x32_bf16(
                        pf[i], wf[j], acc2[i][j], 0, 0, 0);
        }
        __syncthreads();
    }

    // ---- epilogue: + c2 + res, row LN over 256 ----
    const int wn = wave * 64;
    float bv[4];
#pragma unroll
    for (int j = 0; j < 4; ++j) bv[j] = c2[wn + j * 16 + fr];

#pragma unroll
    for (int i = 0; i < 2; ++i) {
#pragma unroll
        for (int r = 0; r < 4; ++r) {
            const int row = i * 16 + quad * 4 + r;
            float ps = 0.f, pq = 0.f;
#pragma unroll
            for (int j = 0; j < 4; ++j) {
                const int gc = wn + j * 16 + fr;
                float v = acc2[i][j][r] + bv[j]
                        + (float)res[(size_t)(m0 + row) * DMODEL + gc];
                acc2[i][j][r] = v;
                ps += v;
                pq += v * v;
            }
#pragma unroll
            for (int off = 1; off < 16; off <<= 1) {
                ps += __shfl_xor(ps, off, 64);
                pq += __shfl_xor(pq, off, 64);
            }
            if (fr == 0) {
                red[row * 8 + wave * 2]     = ps;
                red[row * 8 + wave * 2 + 1] = pq;
            }
        }
    }
    __syncthreads();

#pragma unroll
    for (int i = 0; i < 2; ++i) {
#pragma unroll
        for (int r = 0; r < 4; ++r) {
            const int row = i * 16 + quad * 4 + r;
            f32x4 a = *(const f32x4*)(red + row * 8);
            f32x4 b2 = *(const f32x4*)(red + row * 8 + 4);
            const float s  = a[0] + a[2] + b2[0] + b2[2];
            const float sq = a[1] + a[3] + b2[1] + b2[3];
            const float mu = s * (1.f / DMODEL);
            const float var = sq * (1.f / DMODEL) - mu * mu;
            const float rs = rsqrtf(var + 1e-5f);
#pragma unroll
            for (int j = 0; j < 4; ++j) {
                const int gc = wn + j * 16 + fr;
                float y = (acc2[i][j][r] - mu) * rs * g[gc] + be[gc];
                if (LAST) out32[(size_t)(m0 + row) * DMODEL + gc] = y;
                else      out16[(size_t)(m0 + row) * DMODEL + gc] = (__bf16)y;
            }
        }
    }
}

// ---------------------------------------------------------------------------
// MFMA flash attention, 32x32 tiles. One block per (b,h). (unchanged)
// ---------------------------------------------------------------------------
__global__ __launch_bounds__(1024)
void attn_kernel(const __bf16* __restrict__ qkv, const int* __restrict__ mask,
                 __bf16* __restrict__ ao)
{
    __shared__ __bf16 Ks[512 * 40];
    __shared__ __bf16 Vt[32 * 520];
    __shared__ __bf16 Pq[16 * 32 * 40];
    __shared__ float maskadd[512];

    const int b = blockIdx.x >> 3;
    const int h = blockIdx.x & 7;
    const int t = threadIdx.x;
    const int lane = t & 63;
    const int wave = t >> 6;
    const int cl = lane & 31;
    const int kh = lane >> 5;
    const float scale = 0.17677669529663687f;

    const size_t base = (size_t)b * SEQ * 768;

#pragma unroll
    for (int p = 0; p < 2; ++p) {
        int idx = p * 1024 + t;
        int key = idx >> 2, ch = idx & 3;
        bf16x8 kv = *(const bf16x8*)(qkv + base + (size_t)key * 768 + 256 + h * 32 + ch * 8);
        *(bf16x8*)(Ks + key * 40 + ch * 8) = kv;
        bf16x8 vv = *(const bf16x8*)(qkv + base + (size_t)key * 768 + 512 + h * 32 + ch * 8);
#pragma unroll
        for (int j = 0; j < 8; ++j) Vt[(ch * 8 + j) * 520 + key] = vv[j];
    }
    if (t < 512) maskadd[t] = mask[b * SEQ + t] ? -1e30f : 0.f;
    __syncthreads();

    const int q0 = wave * 32;
    const __bf16* qrow = qkv + base + (size_t)(q0 + cl) * 768 + h * 32;
    bf16x8 qf0 = *(const bf16x8*)(qrow + kh * 8);
    bf16x8 qf1 = *(const bf16x8*)(qrow + 16 + kh * 8);

    f32x16 oacc;
#pragma unroll
    for (int i = 0; i < 16; ++i) oacc[i] = 0.f;
    float lsum = 0.f;
    __bf16* Pw = Pq + wave * 32 * 40;

    for (int kt = 0; kt < SEQ; kt += 32) {
        bf16x8 kf0 = *(const bf16x8*)(Ks + (kt + cl) * 40 + kh * 8);
        bf16x8 kf1 = *(const bf16x8*)(Ks + (kt + cl) * 40 + 16 + kh * 8);
        f32x16 s;
#pragma unroll
        for (int i = 0; i < 16; ++i) s[i] = 0.f;
        s = __builtin_amdgcn_mfma_f32_32x32x16_bf16(kf0, qf0, s, 0, 0, 0);
        s = __builtin_amdgcn_mfma_f32_32x32x16_bf16(kf1, qf1, s, 0, 0, 0);
        float pv[16];
#pragma unroll
        for (int g = 0; g < 4; ++g) {
            f32x4 mv = *(const f32x4*)(maskadd + kt + 8 * g + 4 * kh);
#pragma unroll
            for (int r = 0; r < 4; ++r) {
                float e = __expf(s[g * 4 + r] * scale + mv[r]);
                pv[g * 4 + r] = e;
                lsum += e;
            }
        }
#pragma unroll
        for (int g = 0; g < 4; ++g) {
            bf16x4 pb;
#pragma unroll
            for (int r = 0; r < 4; ++r) pb[r] = (__bf16)pv[g * 4 + r];
            *(bf16x4*)(Pw + cl * 40 + 8 * g + 4 * kh) = pb;
        }
        bf16x8 pf0 = *(const bf16x8*)(Pw + cl * 40 + kh * 8);
        bf16x8 pf1 = *(const bf16x8*)(Pw + cl * 40 + 16 + kh * 8);
        bf16x8 vf0 = *(const bf16x8*)(Vt + cl * 520 + kt + kh * 8);
        bf16x8 vf1 = *(const bf16x8*)(Vt + cl * 520 + kt + 16 + kh * 8);
        oacc = __builtin_amdgcn_mfma_f32_32x32x16_bf16(vf0, pf0, oacc, 0, 0, 0);
        oacc = __builtin_amdgcn_mfma_f32_32x32x16_bf16(vf1, pf1, oacc, 0, 0, 0);
    }

    lsum += __shfl_xor(lsum, 32);
    const float inv = (lsum > 0.f) ? 1.f / lsum : 0.f;
    __bf16* orow = ao + (size_t)(b * SEQ + q0 + cl) * DMODEL + h * 32;
#pragma unroll
    for (int g = 0; g < 4; ++g) {
        bf16x4 w;
#pragma unroll
        for (int r = 0; r < 4; ++r) w[r] = (__bf16)(oacc[g * 4 + r] * inv);
        *(bf16x4*)(orow + 8 * g + 4 * kh) = w;
    }
}

// ---------------------------------------------------------------------------
extern "C" void kernel_launch(void* const* d_in, const int* in_sizes, int n_in,
                              void* d_out, int out_size, void* d_ws, size_t ws_size,
                              hipStream_t stream)
{
    const float* x   = (const float*)d_in[0];
    const int*   mask= (const int*)d_in[1];
    const float* Win = (const float*)d_in[2];
    const float* bin = (const float*)d_in[3];
    const float* Wq  = (const float*)d_in[4];
    const float* bq  = (const float*)d_in[5];
    const float* Wk  = (const float*)d_in[6];
    const float* bk  = (const float*)d_in[7];
    const float* Wv  = (const float*)d_in[8];
    const float* bv  = (const float*)d_in[9];
    const float* Wo  = (const float*)d_in[10];
    const float* bo  = (const float*)d_in[11];
    const float* g1  = (const float*)d_in[12];
    const float* b1  = (const float*)d_in[13];
    const float* W1  = (const float*)d_in[14];
    const float* c1  = (const float*)d_in[15];
    const float* W2  = (const float*)d_in[16];
    const float* c2  = (const float*)d_in[17];
    const float* g2  = (const float*)d_in[18];
    const float* b2  = (const float*)d_in[19];

    char* ws = (char*)d_ws;
    size_t off = 0;
    auto alloc = [&](size_t bytes) -> void* {
        void* p = ws + off;
        off += (bytes + 255) & ~(size_t)255;
        return p;
    };
    __bf16* hA   = (__bf16*)alloc((size_t)MTOK * 256 * 2);  // residual stream
    __bf16* hB   = (__bf16*)alloc((size_t)MTOK * 256 * 2);  // LN1 output
    __bf16* qkv  = (__bf16*)alloc((size_t)MTOK * 768 * 2);  // 24 MB
    __bf16* ao   = (__bf16*)alloc((size_t)MTOK * 256 * 2);
    __bf16* wqkv = (__bf16*)alloc((size_t)3 * 768 * 256 * 2);
    __bf16* wot  = (__bf16*)alloc((size_t)3 * 256 * 256 * 2);
    __bf16* w1f  = (__bf16*)alloc((size_t)3 * 1024 * 256 * 2);
    __bf16* w2f  = (__bf16*)alloc((size_t)3 * 256 * 1024 * 2);
    float*  bqkv = (float*)alloc((size_t)3 * 768 * 4);

    prep_kernel<<<dim3(2313 + MTOK / 8), dim3(256), 0, stream>>>(
        Wq, Wk, Wv, Wo, W1, W2, bq, bk, bv, wqkv, wot, w1f, w2f, bqkv,
        x, Win, bin, hA);

    for (int l = 0; l < NLAYER; ++l) {
        // QKV: [16384,256]bf16 @ [256,768] -> bf16 qkv  (persistent-B)
        gemm_kernel<0><<<dim3(128, 6), dim3(256), 0, stream>>>(
            hA, wqkv + (size_t)l * 768 * 256, bqkv + l * 768, qkv, 768);
        // flash attention (one block per (b,h))
        attn_kernel<<<dim3(256), dim3(1024), 0, stream>>>(qkv, mask, ao);
        // Wo + residual + LN1 fused: hB = LN(hA + ao@Wo + bo)
        gemm_ln_kernel<0><<<dim3(MTOK / 32), dim3(256), 0, stream>>>(
            ao, wot + (size_t)l * 65536, bo + l * 256, hA,
            g1 + l * 256, b1 + l * 256, hB, nullptr, 256);
        // Fused FF block: hA = LN(hB + relu(hB@W1+c1)@W2 + c2)  (last -> d_out)
        if (l == 2) {
            ff_kernel<1><<<dim3(MTOK / 32), dim3(256), 0, stream>>>(
                hB, w1f + (size_t)l * 262144, c1 + l * 1024,
                w2f + (size_t)l * 262144, c2 + l * 256, hB,
                g2 + l * 256, b2 + l * 256, nullptr, (float*)d_out);
        } else {
            ff_kernel<0><<<dim3(MTOK / 32), dim3(256), 0, stream>>>(
                hB, w1f + (size_t)l * 262144, c1 + l * 1024,
                w2f + (size_t)l * 262144, c2 + l * 256, hB,
                g2 + l * 256, b2 + l * 256, hA, nullptr);
        }
    }
}